// Round 8
// baseline (840.361 us; speedup 1.0000x reference)
//
#include <hip/hip_runtime.h>
#include <hip/hip_bf16.h>

// ---------------------------------------------------------------------------
// PAWSA fused windowed attention, MI355X / gfx950 — round 8: persistent blocks.
// Inputs f32, output f32 (out0 [8192,49,96], out1 v_hw [8,3,96] at elem
// offset 38,535,168).
// Grid 768 (=256 CU x 3 resident); each block loops windows bid, bid+768, ...
//   - qkv_w held in registers (wave-split 18 N-tiles as 5/5/5/5 with overlap
//     at 13,14 -> duplicate identical writes, benign), loaded once per block.
//   - X tile loaded global->registers directly (no LDS round trip).
//   - 2 barriers per window; mask loads issued at loop top (hidden).
//   - bias_table/qkv_b/proj_b/REL_IDX hoisted out of the window loop.
// LDS 42,792 B -> 3 blocks/CU.
// ---------------------------------------------------------------------------

typedef __bf16 bf16x8 __attribute__((ext_vector_type(8)));
typedef float  f32x4  __attribute__((ext_vector_type(4)));
using bf16 = __hip_bfloat16;

#define SCALE 0.17677669529663687f   // 32^-0.5
#define NBLK  768

// LDS partition (units: 16-bit elements)
#define LDS_XQ    0       // [52][104] q (rows<52) -> O (rows<49)
#define LDS_K     5408    // [52][104] k   (tile-3 overreads spill into P: finite)
#define LDS_P     10816   // [52][68]  P (bf16 probs, per head; zero-init once)
#define LDS_VT    14352   // [96][68]  v transposed: vt[h*32+d][token]
#define LDS_BIAS  20880   // [516]     bias_table (bf16)
#define LDS_TOT   21396   // shorts -> 42,792 bytes

static __device__ inline float s2f(short s) {
    unsigned int u = ((unsigned int)(unsigned short)s) << 16;
    float f;
    __builtin_memcpy(&f, &u, 4);
    return f;
}
static __device__ inline short f2s(float f) {
    bf16 h = __float2bfloat16(f);
    short s;
    __builtin_memcpy(&s, &h, 2);
    return s;
}
static __device__ inline bf16x8 ldw8(const float* p) {
    f32x4 a = *reinterpret_cast<const f32x4*>(p);
    f32x4 b = *reinterpret_cast<const f32x4*>(p + 4);
    bf16x8 r;
    #pragma unroll
    for (int i = 0; i < 4; ++i) {
        r[i]     = (__bf16)a[i];
        r[i + 4] = (__bf16)b[i];
    }
    return r;
}

__global__ __launch_bounds__(256, 3)
void pawsa_main(const float* __restrict__ x, const float* __restrict__ mask,
                const float* __restrict__ uk, const float* __restrict__ fg,
                const float* __restrict__ bg,
                const float* __restrict__ qkv_w, const float* __restrict__ qkv_b,
                const float* __restrict__ proj_w, const float* __restrict__ proj_b,
                const float* __restrict__ bias_table, float* __restrict__ out)
{
    __shared__ short smem[LDS_TOT];

    const int tid  = threadIdx.x;
    const int bid  = blockIdx.x;
    const int lane = tid & 63;
    const int wid  = tid >> 6;         // wave id 0..3
    const int lr   = lane & 15;        // row/col within 16-tile
    const int lg   = lane >> 4;        // k-group 0..3

    // ---------------- once per block ----------------
    for (int i = tid; i < 516; i += 256) smem[LDS_BIAS + i] = f2s(bias_table[i]);
    for (int i = tid; i < 3536; i += 256) smem[LDS_P + i] = 0;  // NaN-safety (window 0)

    // wave-split QKV N-tiles: 0-4, 5-9, 10-14, 13-17 (13,14 duplicated: benign)
    const int nt0 = (wid < 3) ? wid * 5 : 13;

    bf16x8 wf[5][3];                   // qkv_w fragments, resident all kernel
    float  qb[5];                      // qkv_b per owned output channel
    #pragma unroll
    for (int i = 0; i < 5; ++i) {
        int o = (nt0 + i) * 16 + lr;
        qb[i] = qkv_b[o];
        #pragma unroll
        for (int ks = 0; ks < 3; ++ks)
            wf[i][ks] = ldw8(qkv_w + o * 96 + ks * 32 + lg * 8);
    }
    float pbv[6];                      // proj bias per owned output col
    #pragma unroll
    for (int nt = 0; nt < 6; ++nt) pbv[nt] = proj_b[nt * 16 + lr];

    // REL_IDX packed (4 x u8 per int), loop-invariant
    int bidxp[4];
    #pragma unroll
    for (int nt = 0; nt < 4; ++nt) {
        int c = nt * 16 + lr;
        int p = 0;
        #pragma unroll
        for (int j = 0; j < 4; ++j) {
            int n = wid * 16 + lg * 4 + j;
            int idx = 171;
            if (c < 49) {
                idx = (n / 7 - c / 7 + 6) * 13 + ((n % 7) - (c % 7) + 6);
                if (idx > 171) idx = 171;     // garbage rows n>=49 (discarded)
                if (idx < 0)   idx = 0;
            } else if (c < 52) {
                idx = 169 + (c - 49);
            }
            p |= idx << (8 * j);
        }
        bidxp[nt] = p;
    }
    __syncthreads();

    // ---------------- window loop ----------------
    for (int w = bid; w < 8192; w += NBLK) {
        const int b  = w >> 10;
        const int wi = w & 1023;

        // mask loads (issued early; consumed in heads)
        float mk[4][4];
        #pragma unroll
        for (int nt = 0; nt < 4; ++nt) {
            int c = nt * 16 + lr;
            #pragma unroll
            for (int j = 0; j < 4; ++j) {
                int n = wid * 16 + lg * 4 + j;
                float m = 0.f;
                if (c < 49 && n < 49)
                    m = mask[(size_t)wi * 2401 + n * 49 + c];
                mk[nt][j] = m;
            }
        }

        // X tile -> registers directly (rows<49 x, 49-51 priors, >=52 zero)
        bf16x8 af[3][4];
        #pragma unroll
        for (int mt = 0; mt < 4; ++mt) {
            int n = mt * 16 + lr;
            #pragma unroll
            for (int ks = 0; ks < 3; ++ks) {
                bf16x8 a = (bf16x8)0;
                if (n < 49) {
                    a = ldw8(x + ((size_t)w * 49 + n) * 96 + ks * 32 + lg * 8);
                } else if (n < 52) {
                    const float* pr = (n == 49) ? uk : (n == 50) ? fg : bg;
                    a = ldw8(pr + b * 96 + ks * 32 + lg * 8);
                }
                af[ks][mt] = a;
            }
        }
        __syncthreads();   // prev window's LDS reads done; loads drained

        // ---- QKV: register-resident weights, immediate scatter ----
        #pragma unroll
        for (int i = 0; i < 5; ++i) {
            f32x4 acc[4] = {(f32x4)0.f, (f32x4)0.f, (f32x4)0.f, (f32x4)0.f};
            #pragma unroll
            for (int ks = 0; ks < 3; ++ks)
                #pragma unroll
                for (int mt = 0; mt < 4; ++mt)
                    acc[mt] = __builtin_amdgcn_mfma_f32_16x16x32_bf16(
                        af[ks][mt], wf[i][ks], acc[mt], 0, 0, 0);
            int o = (nt0 + i) * 16 + lr;
            int s = o / 96;                   // 0=q 1=k 2=v
            int rem = o - s * 96;
            #pragma unroll
            for (int mt = 0; mt < 4; ++mt) {
                #pragma unroll
                for (int j = 0; j < 4; ++j) {
                    int n = mt * 16 + lg * 4 + j;
                    short hv = f2s(acc[mt][j] + qb[i]);
                    if (s == 0)      { if (n < 52) smem[LDS_XQ + n * 104 + rem] = hv; }
                    else if (s == 1) { if (n < 52) smem[LDS_K  + n * 104 + rem] = hv; }
                    else             smem[LDS_VT + rem * 68 + n] = hv;
                }
            }
        }
        __syncthreads();

        // ---- per-head attention (wave-private rows; no barriers) ----
        #pragma unroll
        for (int h = 0; h < 3; ++h) {
            bf16x8 aq = *reinterpret_cast<const bf16x8*>(
                &smem[LDS_XQ + (wid * 16 + lr) * 104 + h * 32 + lg * 8]);
            f32x4 sacc[4];
            #pragma unroll
            for (int nt = 0; nt < 4; ++nt) {
                bf16x8 bk = *reinterpret_cast<const bf16x8*>(
                    &smem[LDS_K + (nt * 16 + lr) * 104 + h * 32 + lg * 8]);
                sacc[nt] = __builtin_amdgcn_mfma_f32_16x16x32_bf16(aq, bk, (f32x4)0.f, 0, 0, 0);
            }
            float lgt[4][4];
            #pragma unroll
            for (int nt = 0; nt < 4; ++nt) {
                int c = nt * 16 + lr;
                #pragma unroll
                for (int j = 0; j < 4; ++j) {
                    float v = -1e30f;
                    if (c < 52) {
                        int idx = (bidxp[nt] >> (8 * j)) & 255;
                        v = sacc[nt][j] * SCALE
                            + s2f(smem[LDS_BIAS + idx * 3 + h]) + mk[nt][j];
                    }
                    lgt[nt][j] = v;
                }
            }
            float pr[4][4];
            #pragma unroll
            for (int j = 0; j < 4; ++j) {
                float m = fmaxf(fmaxf(lgt[0][j], lgt[1][j]), fmaxf(lgt[2][j], lgt[3][j]));
                m = fmaxf(m, __shfl_xor(m, 1));
                m = fmaxf(m, __shfl_xor(m, 2));
                m = fmaxf(m, __shfl_xor(m, 4));
                m = fmaxf(m, __shfl_xor(m, 8));
                float sum = 0.f;
                #pragma unroll
                for (int nt = 0; nt < 4; ++nt) {
                    pr[nt][j] = __expf(lgt[nt][j] - m);
                    sum += pr[nt][j];
                }
                sum += __shfl_xor(sum, 1);
                sum += __shfl_xor(sum, 2);
                sum += __shfl_xor(sum, 4);
                sum += __shfl_xor(sum, 8);
                float inv = 1.0f / sum;
                #pragma unroll
                for (int nt = 0; nt < 4; ++nt) pr[nt][j] *= inv;
            }
            #pragma unroll
            for (int nt = 0; nt < 4; ++nt)
                #pragma unroll
                for (int j = 0; j < 4; ++j) {
                    int prow = wid * 16 + lg * 4 + j;
                    if (prow < 52)
                        smem[LDS_P + prow * 68 + nt * 16 + lr] = f2s(pr[nt][j]);
                }

            // O_h = P @ V (K=52 padded to 64; P cols 52-63 exact zeros)
            f32x4 ov[2] = {(f32x4)0.f, (f32x4)0.f};
            #pragma unroll
            for (int ks = 0; ks < 2; ++ks) {
                bf16x8 ap = *reinterpret_cast<const bf16x8*>(
                    &smem[LDS_P + (wid * 16 + lr) * 68 + ks * 32 + lg * 8]);
                #pragma unroll
                for (int nt2 = 0; nt2 < 2; ++nt2) {
                    bf16x8 bv = *reinterpret_cast<const bf16x8*>(
                        &smem[LDS_VT + (h * 32 + nt2 * 16 + lr) * 68 + ks * 32 + lg * 8]);
                    ov[nt2] = __builtin_amdgcn_mfma_f32_16x16x32_bf16(ap, bv, ov[nt2], 0, 0, 0);
                }
            }
            #pragma unroll
            for (int nt2 = 0; nt2 < 2; ++nt2)
                #pragma unroll
                for (int j = 0; j < 4; ++j) {
                    int orow = wid * 16 + lg * 4 + j;
                    if (orow < 52)
                        smem[LDS_XQ + orow * 104 + h * 32 + nt2 * 16 + lr]
                            = f2s(ov[nt2][j]);
                }
        }

        // ---- projection (wave-private rows) ----
        f32x4 po[6];
        #pragma unroll
        for (int nt = 0; nt < 6; ++nt) po[nt] = (f32x4)0.f;
        #pragma unroll
        for (int ks = 0; ks < 3; ++ks) {
            bf16x8 a = *reinterpret_cast<const bf16x8*>(
                &smem[LDS_XQ + (wid * 16 + lr) * 104 + ks * 32 + lg * 8]);
            #pragma unroll
            for (int nt = 0; nt < 6; ++nt) {
                bf16x8 bp = ldw8(proj_w + (nt * 16 + lr) * 96 + ks * 32 + lg * 8);
                po[nt] = __builtin_amdgcn_mfma_f32_16x16x32_bf16(a, bp, po[nt], 0, 0, 0);
            }
        }
        #pragma unroll
        for (int nt = 0; nt < 6; ++nt) {
            #pragma unroll
            for (int j = 0; j < 4; ++j) {
                int n = wid * 16 + lg * 4 + j;
                if (n < 49)
                    out[((size_t)w * 49 + n) * 96 + nt * 16 + lr] = po[nt][j] + pbv[nt];
            }
        }
    }
}

// ---------------- prior highway: v_hw = proj(v(qkv(prior))) ----------------
__global__ __launch_bounds__(128)
void pawsa_prior(const float* __restrict__ uk, const float* __restrict__ fg,
                 const float* __restrict__ bg,
                 const float* __restrict__ qkv_w, const float* __restrict__ qkv_b,
                 const float* __restrict__ proj_w, const float* __restrict__ proj_b,
                 float* __restrict__ out_vhw)
{
    int blk = blockIdx.x;             // 24 = 8 batches * 3 priors
    int b = blk / 3, p = blk % 3;
    int t = threadIdx.x;
    __shared__ float prr[96], vf[96];
    const float* src = (p == 0) ? uk : (p == 1) ? fg : bg;
    if (t < 96) prr[t] = src[b * 96 + t];
    __syncthreads();
    if (t < 96) {
        float acc = qkv_b[192 + t];
        for (int k = 0; k < 96; ++k)
            acc += prr[k] * qkv_w[(192 + t) * 96 + k];
        vf[t] = acc;
    }
    __syncthreads();
    if (t < 96) {
        float acc = proj_b[t];
        for (int c = 0; c < 96; ++c)
            acc += vf[c] * proj_w[t * 96 + c];
        out_vhw[(b * 3 + p) * 96 + t] = acc;
    }
}

extern "C" void kernel_launch(void* const* d_in, const int* in_sizes, int n_in,
                              void* d_out, int out_size, void* d_ws, size_t ws_size,
                              hipStream_t stream) {
    const float* x          = (const float*)d_in[0];
    const float* mask       = (const float*)d_in[1];
    const float* uk         = (const float*)d_in[2];
    const float* fg         = (const float*)d_in[3];
    const float* bg         = (const float*)d_in[4];
    const float* qkv_w      = (const float*)d_in[5];
    const float* qkv_b      = (const float*)d_in[6];
    const float* proj_w     = (const float*)d_in[7];
    const float* proj_b     = (const float*)d_in[8];
    const float* bias_table = (const float*)d_in[9];
    float* out = (float*)d_out;

    pawsa_prior<<<24, 128, 0, stream>>>(uk, fg, bg, qkv_w, qkv_b, proj_w, proj_b,
                                        out + (size_t)8192 * 49 * 96);
    pawsa_main<<<NBLK, 256, 0, stream>>>(x, mask, uk, fg, bg, qkv_w, qkv_b,
                                         proj_w, proj_b, bias_table, out);
}

// Round 9
// 688.496 us; speedup vs baseline: 1.2206x; 1.2206x over previous
//
#include <hip/hip_runtime.h>
#include <hip/hip_bf16.h>

// ---------------------------------------------------------------------------
// PAWSA fused windowed attention, MI355X / gfx950 — round 9.
// Inputs f32, output f32 (out0 [8192,49,96], out1 v_hw [8,3,96] at elem
// offset 38,535,168). One block per window (8192 x 256), bf16 MFMA 16x16x32.
// vs R7: X tile loaded global->registers (no staging, rows>=52 are register
// zeros), straight-line QKV (all waves 5 tiles, 13-14 duplicated: benign
// identical writes), mask loads issued first, 2 barriers total.
// LDS 42,792 B -> 3 blocks/CU. Short register lifetimes -> no spill (check:
// FETCH_SIZE ~110 MB; explosion would indicate scratch traffic).
// ---------------------------------------------------------------------------

typedef __bf16 bf16x8 __attribute__((ext_vector_type(8)));
typedef float  f32x4  __attribute__((ext_vector_type(4)));
using bf16 = __hip_bfloat16;

#define SCALE 0.17677669529663687f   // 32^-0.5

// LDS partition (units: 16-bit elements)
#define LDS_XQ    0       // [52][104] q (rows<52) -> O (rows<49)
#define LDS_K     5408    // [52][104] k  (reads of rows 52-63 spill into P: finite/masked)
#define LDS_P     10816   // [52][68]  P (bf16 probs, per head)
#define LDS_VT    14352   // [96][68]  v transposed: vt[h*32+d][token]
#define LDS_BIAS  20880   // [516]     bias_table (bf16)
#define LDS_TOT   21396   // shorts -> 42,792 bytes

static __device__ inline float s2f(short s) {
    unsigned int u = ((unsigned int)(unsigned short)s) << 16;
    float f;
    __builtin_memcpy(&f, &u, 4);
    return f;
}
static __device__ inline short f2s(float f) {
    bf16 h = __float2bfloat16(f);
    short s;
    __builtin_memcpy(&s, &h, 2);
    return s;
}
static __device__ inline bf16x8 ldw8(const float* p) {
    f32x4 a = *reinterpret_cast<const f32x4*>(p);
    f32x4 b = *reinterpret_cast<const f32x4*>(p + 4);
    bf16x8 r;
    #pragma unroll
    for (int i = 0; i < 4; ++i) {
        r[i]     = (__bf16)a[i];
        r[i + 4] = (__bf16)b[i];
    }
    return r;
}

__global__ __launch_bounds__(256, 3)
void pawsa_main(const float* __restrict__ x, const float* __restrict__ mask,
                const float* __restrict__ uk, const float* __restrict__ fg,
                const float* __restrict__ bg,
                const float* __restrict__ qkv_w, const float* __restrict__ qkv_b,
                const float* __restrict__ proj_w, const float* __restrict__ proj_b,
                const float* __restrict__ bias_table, float* __restrict__ out)
{
    __shared__ short smem[LDS_TOT];

    const int tid  = threadIdx.x;
    const int w    = blockIdx.x;       // window id
    const int b    = w >> 10;          // batch (nW = 1024)
    const int wi   = w & 1023;         // window-in-batch
    const int lane = tid & 63;
    const int wid  = tid >> 6;         // wave id 0..3
    const int lr   = lane & 15;        // row/col within 16-tile
    const int lg   = lane >> 4;        // k-group 0..3

    // ---- mask loads first (in flight under everything below) ----
    float mk[4][4];
    #pragma unroll
    for (int nt = 0; nt < 4; ++nt) {
        int c = nt * 16 + lr;
        #pragma unroll
        for (int j = 0; j < 4; ++j) {
            int n = wid * 16 + lg * 4 + j;
            float m = 0.f;
            if (c < 49 && n < 49)
                m = mask[(size_t)wi * 2401 + n * 49 + c];
            mk[nt][j] = m;
        }
    }

    // ---- weight fragments + bias (wave-split tiles: 0-4,5-9,10-14,13-17) ----
    const int nt0 = (wid < 3) ? wid * 5 : 13;
    bf16x8 wfr[5][3];
    float  qb[5];
    #pragma unroll
    for (int i = 0; i < 5; ++i) {
        int o = (nt0 + i) * 16 + lr;
        qb[i] = qkv_b[o];
        #pragma unroll
        for (int ks = 0; ks < 3; ++ks)
            wfr[i][ks] = ldw8(qkv_w + o * 96 + ks * 32 + lg * 8);
    }

    // ---- X tile -> registers (rows<49 x, 49-51 priors, >=52 zero) ----
    bf16x8 af[3][4];
    #pragma unroll
    for (int mt = 0; mt < 4; ++mt) {
        int n = mt * 16 + lr;
        #pragma unroll
        for (int ks = 0; ks < 3; ++ks) {
            bf16x8 a = (bf16x8)0;
            if (n < 49) {
                a = ldw8(x + ((size_t)w * 49 + n) * 96 + ks * 32 + lg * 8);
            } else if (n < 52) {
                const float* pr = (n == 49) ? uk : (n == 50) ? fg : bg;
                a = ldw8(pr + b * 96 + ks * 32 + lg * 8);
            }
            af[ks][mt] = a;
        }
    }

    // ---- bias_table -> LDS (covered by the post-scatter barrier) ----
    for (int i = tid; i < 516; i += 256) smem[LDS_BIAS + i] = f2s(bias_table[i]);

    // ---- QKV GEMM: one tile at a time, immediate scatter ----
    #pragma unroll
    for (int i = 0; i < 5; ++i) {
        f32x4 acc[4] = {(f32x4)0.f, (f32x4)0.f, (f32x4)0.f, (f32x4)0.f};
        #pragma unroll
        for (int ks = 0; ks < 3; ++ks)
            #pragma unroll
            for (int mt = 0; mt < 4; ++mt)
                acc[mt] = __builtin_amdgcn_mfma_f32_16x16x32_bf16(
                    af[ks][mt], wfr[i][ks], acc[mt], 0, 0, 0);
        int o = (nt0 + i) * 16 + lr;
        int s = o / 96;                   // 0=q 1=k 2=v
        int rem = o - s * 96;
        #pragma unroll
        for (int mt = 0; mt < 4; ++mt) {
            #pragma unroll
            for (int j = 0; j < 4; ++j) {
                int n = mt * 16 + lg * 4 + j;
                short hv = f2s(acc[mt][j] + qb[i]);
                if (s == 0)      { if (n < 52) smem[LDS_XQ + n * 104 + rem] = hv; }
                else if (s == 1) { if (n < 52) smem[LDS_K  + n * 104 + rem] = hv; }
                else             smem[LDS_VT + rem * 68 + n] = hv;
            }
        }
    }
    __syncthreads();
    // From here: K, VT read-only; XQ/P rows wave-private.

    // REL_IDX packed (4 x u8 per int)
    int bidxp[4];
    #pragma unroll
    for (int nt = 0; nt < 4; ++nt) {
        int c = nt * 16 + lr;
        int p = 0;
        #pragma unroll
        for (int j = 0; j < 4; ++j) {
            int n = wid * 16 + lg * 4 + j;
            int idx = 171;
            if (c < 49) {
                idx = (n / 7 - c / 7 + 6) * 13 + ((n % 7) - (c % 7) + 6);
                if (idx > 171) idx = 171;     // garbage rows n>=49 (discarded)
            } else if (c < 52) {
                idx = 169 + (c - 49);
            }
            p |= idx << (8 * j);
        }
        bidxp[nt] = p;
    }

    // ---- per-head attention (wave-private rows; no barriers) ----
    #pragma unroll
    for (int h = 0; h < 3; ++h) {
        bf16x8 aq = *reinterpret_cast<const bf16x8*>(
            &smem[LDS_XQ + (wid * 16 + lr) * 104 + h * 32 + lg * 8]);
        f32x4 sacc[4];
        #pragma unroll
        for (int nt = 0; nt < 4; ++nt) {
            bf16x8 bk = *reinterpret_cast<const bf16x8*>(
                &smem[LDS_K + (nt * 16 + lr) * 104 + h * 32 + lg * 8]);
            sacc[nt] = __builtin_amdgcn_mfma_f32_16x16x32_bf16(aq, bk, (f32x4)0.f, 0, 0, 0);
        }
        float lgt[4][4];
        #pragma unroll
        for (int nt = 0; nt < 4; ++nt) {
            int c = nt * 16 + lr;
            #pragma unroll
            for (int j = 0; j < 4; ++j) {
                float v = -1e30f;
                if (c < 52) {
                    int idx = (bidxp[nt] >> (8 * j)) & 255;
                    v = sacc[nt][j] * SCALE
                        + s2f(smem[LDS_BIAS + idx * 3 + h]) + mk[nt][j];
                }
                lgt[nt][j] = v;
            }
        }
        float pr[4][4];
        #pragma unroll
        for (int j = 0; j < 4; ++j) {
            float m = fmaxf(fmaxf(lgt[0][j], lgt[1][j]), fmaxf(lgt[2][j], lgt[3][j]));
            m = fmaxf(m, __shfl_xor(m, 1));
            m = fmaxf(m, __shfl_xor(m, 2));
            m = fmaxf(m, __shfl_xor(m, 4));
            m = fmaxf(m, __shfl_xor(m, 8));
            float sum = 0.f;
            #pragma unroll
            for (int nt = 0; nt < 4; ++nt) {
                pr[nt][j] = __expf(lgt[nt][j] - m);
                sum += pr[nt][j];
            }
            sum += __shfl_xor(sum, 1);
            sum += __shfl_xor(sum, 2);
            sum += __shfl_xor(sum, 4);
            sum += __shfl_xor(sum, 8);
            float inv = 1.0f / sum;
            #pragma unroll
            for (int nt = 0; nt < 4; ++nt) pr[nt][j] *= inv;
        }
        #pragma unroll
        for (int nt = 0; nt < 4; ++nt)
            #pragma unroll
            for (int j = 0; j < 4; ++j) {
                int prow = wid * 16 + lg * 4 + j;
                if (prow < 52)
                    smem[LDS_P + prow * 68 + nt * 16 + lr] = f2s(pr[nt][j]);
            }

        // O_h = P @ V (K=52 padded to 64; P cols 52-63 exact zeros)
        f32x4 ov[2] = {(f32x4)0.f, (f32x4)0.f};
        #pragma unroll
        for (int ks = 0; ks < 2; ++ks) {
            bf16x8 ap = *reinterpret_cast<const bf16x8*>(
                &smem[LDS_P + (wid * 16 + lr) * 68 + ks * 32 + lg * 8]);
            #pragma unroll
            for (int nt2 = 0; nt2 < 2; ++nt2) {
                bf16x8 bv = *reinterpret_cast<const bf16x8*>(
                    &smem[LDS_VT + (h * 32 + nt2 * 16 + lr) * 68 + ks * 32 + lg * 8]);
                ov[nt2] = __builtin_amdgcn_mfma_f32_16x16x32_bf16(ap, bv, ov[nt2], 0, 0, 0);
            }
        }
        #pragma unroll
        for (int nt2 = 0; nt2 < 2; ++nt2)
            #pragma unroll
            for (int j = 0; j < 4; ++j) {
                int orow = wid * 16 + lg * 4 + j;
                if (orow < 52)
                    smem[LDS_XQ + orow * 104 + h * 32 + nt2 * 16 + lr]
                        = f2s(ov[nt2][j]);
            }
    }

    // ---- projection: [64x96] @ proj_w^T[96x96] (wave-private rows) ----
    f32x4 po[6];
    #pragma unroll
    for (int nt = 0; nt < 6; ++nt) po[nt] = (f32x4)0.f;
    #pragma unroll
    for (int ks = 0; ks < 3; ++ks) {
        bf16x8 a = *reinterpret_cast<const bf16x8*>(
            &smem[LDS_XQ + (wid * 16 + lr) * 104 + ks * 32 + lg * 8]);
        #pragma unroll
        for (int nt = 0; nt < 6; ++nt) {
            bf16x8 bp = ldw8(proj_w + (nt * 16 + lr) * 96 + ks * 32 + lg * 8);
            po[nt] = __builtin_amdgcn_mfma_f32_16x16x32_bf16(a, bp, po[nt], 0, 0, 0);
        }
    }
    #pragma unroll
    for (int nt = 0; nt < 6; ++nt) {
        float pb = proj_b[nt * 16 + lr];
        #pragma unroll
        for (int j = 0; j < 4; ++j) {
            int n = wid * 16 + lg * 4 + j;
            if (n < 49)
                out[((size_t)w * 49 + n) * 96 + nt * 16 + lr] = po[nt][j] + pb;
        }
    }
}

// ---------------- prior highway: v_hw = proj(v(qkv(prior))) ----------------
__global__ __launch_bounds__(128)
void pawsa_prior(const float* __restrict__ uk, const float* __restrict__ fg,
                 const float* __restrict__ bg,
                 const float* __restrict__ qkv_w, const float* __restrict__ qkv_b,
                 const float* __restrict__ proj_w, const float* __restrict__ proj_b,
                 float* __restrict__ out_vhw)
{
    int blk = blockIdx.x;             // 24 = 8 batches * 3 priors
    int b = blk / 3, p = blk % 3;
    int t = threadIdx.x;
    __shared__ float prr[96], vf[96];
    const float* src = (p == 0) ? uk : (p == 1) ? fg : bg;
    if (t < 96) prr[t] = src[b * 96 + t];
    __syncthreads();
    if (t < 96) {
        float acc = qkv_b[192 + t];
        for (int k = 0; k < 96; ++k)
            acc += prr[k] * qkv_w[(192 + t) * 96 + k];
        vf[t] = acc;
    }
    __syncthreads();
    if (t < 96) {
        float acc = proj_b[t];
        for (int c = 0; c < 96; ++c)
            acc += vf[c] * proj_w[t * 96 + c];
        out_vhw[(b * 3 + p) * 96 + t] = acc;
    }
}

extern "C" void kernel_launch(void* const* d_in, const int* in_sizes, int n_in,
                              void* d_out, int out_size, void* d_ws, size_t ws_size,
                              hipStream_t stream) {
    const float* x          = (const float*)d_in[0];
    const float* mask       = (const float*)d_in[1];
    const float* uk         = (const float*)d_in[2];
    const float* fg         = (const float*)d_in[3];
    const float* bg         = (const float*)d_in[4];
    const float* qkv_w      = (const float*)d_in[5];
    const float* qkv_b      = (const float*)d_in[6];
    const float* proj_w     = (const float*)d_in[7];
    const float* proj_b     = (const float*)d_in[8];
    const float* bias_table = (const float*)d_in[9];
    float* out = (float*)d_out;

    pawsa_prior<<<24, 128, 0, stream>>>(uk, fg, bg, qkv_w, qkv_b, proj_w, proj_b,
                                        out + (size_t)8192 * 49 * 96);
    pawsa_main<<<8192, 256, 0, stream>>>(x, mask, uk, fg, bg, qkv_w, qkv_b,
                                         proj_w, proj_b, bias_table, out);
}

// Round 10
// 437.941 us; speedup vs baseline: 1.9189x; 1.5721x over previous
//
#include <hip/hip_runtime.h>
#include <hip/hip_bf16.h>

// ---------------------------------------------------------------------------
// PAWSA fused windowed attention, MI355X / gfx950 — round 10.
// Inputs f32, output f32 (out0 [8192,49,96], out1 v_hw [8,3,96] at elem
// offset 38,535,168). One block per window (8192 x 256), bf16 MFMA 16x16x32.
// = R7's register discipline (weights per-tile, ~70 peak live VGPRs, no
//   residency) + R9's structure (X direct global->reg, single barrier).
// LDS 42,792 B -> 3 blocks/CU.
// Register budget model (R7-R9 evidence): compiler pins arch-VGPR ~84 at
// this occupancy and SPILLS beyond it — never hold >80 live VGPRs.
// ---------------------------------------------------------------------------

typedef __bf16 bf16x8 __attribute__((ext_vector_type(8)));
typedef float  f32x4  __attribute__((ext_vector_type(4)));
using bf16 = __hip_bfloat16;

#define SCALE 0.17677669529663687f   // 32^-0.5

// LDS partition (units: 16-bit elements)
#define LDS_XQ    0       // [52][104] q (rows<52) -> O (rows<49)
#define LDS_K     5408    // [52][104] k  (row-52..63 overreads land in P: finite/masked)
#define LDS_P     10816   // [52][68]  P (bf16 probs, per head)
#define LDS_VT    14352   // [96][68]  v transposed: vt[h*32+d][token]
#define LDS_BIAS  20880   // [516]     bias_table (bf16)
#define LDS_TOT   21396   // shorts -> 42,792 bytes

static __device__ inline float s2f(short s) {
    unsigned int u = ((unsigned int)(unsigned short)s) << 16;
    float f;
    __builtin_memcpy(&f, &u, 4);
    return f;
}
static __device__ inline short f2s(float f) {
    bf16 h = __float2bfloat16(f);
    short s;
    __builtin_memcpy(&s, &h, 2);
    return s;
}
static __device__ inline bf16x8 ldw8(const float* p) {
    f32x4 a = *reinterpret_cast<const f32x4*>(p);
    f32x4 b = *reinterpret_cast<const f32x4*>(p + 4);
    bf16x8 r;
    #pragma unroll
    for (int i = 0; i < 4; ++i) {
        r[i]     = (__bf16)a[i];
        r[i + 4] = (__bf16)b[i];
    }
    return r;
}

__global__ __launch_bounds__(256, 3)
void pawsa_main(const float* __restrict__ x, const float* __restrict__ mask,
                const float* __restrict__ uk, const float* __restrict__ fg,
                const float* __restrict__ bg,
                const float* __restrict__ qkv_w, const float* __restrict__ qkv_b,
                const float* __restrict__ proj_w, const float* __restrict__ proj_b,
                const float* __restrict__ bias_table, float* __restrict__ out)
{
    __shared__ short smem[LDS_TOT];

    const int tid  = threadIdx.x;
    const int w    = blockIdx.x;       // window id
    const int b    = w >> 10;          // batch (nW = 1024)
    const int wi   = w & 1023;         // window-in-batch
    const int lane = tid & 63;
    const int wid  = tid >> 6;         // wave id 0..3
    const int lr   = lane & 15;        // row/col within 16-tile
    const int lg   = lane >> 4;        // k-group 0..3

    // ---- X tile -> registers directly (rows<49 x, 49-51 priors, >=52 zero) --
    bf16x8 af[3][4];
    #pragma unroll
    for (int mt = 0; mt < 4; ++mt) {
        int n = mt * 16 + lr;
        #pragma unroll
        for (int ks = 0; ks < 3; ++ks) {
            bf16x8 a = (bf16x8)0;
            if (n < 49) {
                a = ldw8(x + ((size_t)w * 49 + n) * 96 + ks * 32 + lg * 8);
            } else if (n < 52) {
                const float* pr = (n == 49) ? uk : (n == 50) ? fg : bg;
                a = ldw8(pr + b * 96 + ks * 32 + lg * 8);
            }
            af[ks][mt] = a;
        }
    }

    // ---- bias_table -> LDS (covered by the post-scatter barrier) ----
    for (int i = tid; i < 516; i += 256) smem[LDS_BIAS + i] = f2s(bias_table[i]);

    // ---- QKV GEMM: wave-split tiles (0-4,5-9,10-14,13-17; 13,14 dup benign),
    //      weights loaded per-tile (low register pressure), immediate scatter --
    const int nt0 = (wid < 3) ? wid * 5 : 13;
    #pragma unroll
    for (int i = 0; i < 5; ++i) {
        int o = (nt0 + i) * 16 + lr;          // output channel 0..287
        bf16x8 bw0 = ldw8(qkv_w + o * 96 + 0 * 32 + lg * 8);
        bf16x8 bw1 = ldw8(qkv_w + o * 96 + 1 * 32 + lg * 8);
        bf16x8 bw2 = ldw8(qkv_w + o * 96 + 2 * 32 + lg * 8);
        float  qb  = qkv_b[o];
        f32x4 acc[4] = {(f32x4)0.f, (f32x4)0.f, (f32x4)0.f, (f32x4)0.f};
        #pragma unroll
        for (int mt = 0; mt < 4; ++mt) {
            acc[mt] = __builtin_amdgcn_mfma_f32_16x16x32_bf16(af[0][mt], bw0, acc[mt], 0, 0, 0);
            acc[mt] = __builtin_amdgcn_mfma_f32_16x16x32_bf16(af[1][mt], bw1, acc[mt], 0, 0, 0);
            acc[mt] = __builtin_amdgcn_mfma_f32_16x16x32_bf16(af[2][mt], bw2, acc[mt], 0, 0, 0);
        }
        int s = o / 96;                       // 0=q 1=k 2=v
        int rem = o - s * 96;
        #pragma unroll
        for (int mt = 0; mt < 4; ++mt) {
            #pragma unroll
            for (int j = 0; j < 4; ++j) {
                int n = mt * 16 + lg * 4 + j;
                short hv = f2s(acc[mt][j] + qb);
                if (s == 0)      { if (n < 52) smem[LDS_XQ + n * 104 + rem] = hv; }
                else if (s == 1) { if (n < 52) smem[LDS_K  + n * 104 + rem] = hv; }
                else             smem[LDS_VT + rem * 68 + n] = hv;
            }
        }
    }

    // ---- mask loads (issued before barrier; consumed in heads) ----
    float mk[4][4];
    #pragma unroll
    for (int nt = 0; nt < 4; ++nt) {
        int c = nt * 16 + lr;
        #pragma unroll
        for (int j = 0; j < 4; ++j) {
            int n = wid * 16 + lg * 4 + j;
            float m = 0.f;
            if (c < 49 && n < 49)
                m = mask[(size_t)wi * 2401 + n * 49 + c];
            mk[nt][j] = m;
        }
    }

    __syncthreads();
    // From here: K, VT read-only; XQ/P rows wave-private.

    // REL_IDX packed (4 x u8 per int)
    int bidxp[4];
    #pragma unroll
    for (int nt = 0; nt < 4; ++nt) {
        int c = nt * 16 + lr;
        int p = 0;
        #pragma unroll
        for (int j = 0; j < 4; ++j) {
            int n = wid * 16 + lg * 4 + j;
            int idx = 171;
            if (c < 49) {
                idx = (n / 7 - c / 7 + 6) * 13 + ((n % 7) - (c % 7) + 6);
                if (idx > 171) idx = 171;     // garbage rows n>=49 (discarded)
            } else if (c < 52) {
                idx = 169 + (c - 49);
            }
            p |= idx << (8 * j);
        }
        bidxp[nt] = p;
    }

    // ---- per-head attention (wave-private rows; no barriers) ----
    #pragma unroll
    for (int h = 0; h < 3; ++h) {
        bf16x8 aq = *reinterpret_cast<const bf16x8*>(
            &smem[LDS_XQ + (wid * 16 + lr) * 104 + h * 32 + lg * 8]);
        f32x4 sacc[4];
        #pragma unroll
        for (int nt = 0; nt < 4; ++nt) {
            bf16x8 bk = *reinterpret_cast<const bf16x8*>(
                &smem[LDS_K + (nt * 16 + lr) * 104 + h * 32 + lg * 8]);
            sacc[nt] = __builtin_amdgcn_mfma_f32_16x16x32_bf16(aq, bk, (f32x4)0.f, 0, 0, 0);
        }
        float lgt[4][4];
        #pragma unroll
        for (int nt = 0; nt < 4; ++nt) {
            int c = nt * 16 + lr;
            #pragma unroll
            for (int j = 0; j < 4; ++j) {
                float v = -1e30f;
                if (c < 52) {
                    int idx = (bidxp[nt] >> (8 * j)) & 255;
                    v = sacc[nt][j] * SCALE
                        + s2f(smem[LDS_BIAS + idx * 3 + h]) + mk[nt][j];
                }
                lgt[nt][j] = v;
            }
        }
        float pr[4][4];
        #pragma unroll
        for (int j = 0; j < 4; ++j) {
            float m = fmaxf(fmaxf(lgt[0][j], lgt[1][j]), fmaxf(lgt[2][j], lgt[3][j]));
            m = fmaxf(m, __shfl_xor(m, 1));
            m = fmaxf(m, __shfl_xor(m, 2));
            m = fmaxf(m, __shfl_xor(m, 4));
            m = fmaxf(m, __shfl_xor(m, 8));
            float sum = 0.f;
            #pragma unroll
            for (int nt = 0; nt < 4; ++nt) {
                pr[nt][j] = __expf(lgt[nt][j] - m);
                sum += pr[nt][j];
            }
            sum += __shfl_xor(sum, 1);
            sum += __shfl_xor(sum, 2);
            sum += __shfl_xor(sum, 4);
            sum += __shfl_xor(sum, 8);
            float inv = 1.0f / sum;
            #pragma unroll
            for (int nt = 0; nt < 4; ++nt) pr[nt][j] *= inv;
        }
        #pragma unroll
        for (int nt = 0; nt < 4; ++nt)
            #pragma unroll
            for (int j = 0; j < 4; ++j) {
                int prow = wid * 16 + lg * 4 + j;
                if (prow < 52)
                    smem[LDS_P + prow * 68 + nt * 16 + lr] = f2s(pr[nt][j]);
            }

        // O_h = P @ V (K=52 padded to 64; P cols 52-63 exact zeros)
        f32x4 ov[2] = {(f32x4)0.f, (f32x4)0.f};
        #pragma unroll
        for (int ks = 0; ks < 2; ++ks) {
            bf16x8 ap = *reinterpret_cast<const bf16x8*>(
                &smem[LDS_P + (wid * 16 + lr) * 68 + ks * 32 + lg * 8]);
            #pragma unroll
            for (int nt2 = 0; nt2 < 2; ++nt2) {
                bf16x8 bv = *reinterpret_cast<const bf16x8*>(
                    &smem[LDS_VT + (h * 32 + nt2 * 16 + lr) * 68 + ks * 32 + lg * 8]);
                ov[nt2] = __builtin_amdgcn_mfma_f32_16x16x32_bf16(ap, bv, ov[nt2], 0, 0, 0);
            }
        }
        #pragma unroll
        for (int nt2 = 0; nt2 < 2; ++nt2)
            #pragma unroll
            for (int j = 0; j < 4; ++j) {
                int orow = wid * 16 + lg * 4 + j;
                if (orow < 52)
                    smem[LDS_XQ + orow * 104 + h * 32 + nt2 * 16 + lr]
                        = f2s(ov[nt2][j]);
            }
    }

    // ---- projection: [64x96] @ proj_w^T[96x96] (wave-private rows) ----
    f32x4 po[6];
    #pragma unroll
    for (int nt = 0; nt < 6; ++nt) po[nt] = (f32x4)0.f;
    #pragma unroll
    for (int ks = 0; ks < 3; ++ks) {
        bf16x8 a = *reinterpret_cast<const bf16x8*>(
            &smem[LDS_XQ + (wid * 16 + lr) * 104 + ks * 32 + lg * 8]);
        #pragma unroll
        for (int nt = 0; nt < 6; ++nt) {
            bf16x8 bp = ldw8(proj_w + (nt * 16 + lr) * 96 + ks * 32 + lg * 8);
            po[nt] = __builtin_amdgcn_mfma_f32_16x16x32_bf16(a, bp, po[nt], 0, 0, 0);
        }
    }
    #pragma unroll
    for (int nt = 0; nt < 6; ++nt) {
        float pb = proj_b[nt * 16 + lr];
        #pragma unroll
        for (int j = 0; j < 4; ++j) {
            int n = wid * 16 + lg * 4 + j;
            if (n < 49)
                out[((size_t)w * 49 + n) * 96 + nt * 16 + lr] = po[nt][j] + pb;
        }
    }
}

// ---------------- prior highway: v_hw = proj(v(qkv(prior))) ----------------
__global__ __launch_bounds__(128)
void pawsa_prior(const float* __restrict__ uk, const float* __restrict__ fg,
                 const float* __restrict__ bg,
                 const float* __restrict__ qkv_w, const float* __restrict__ qkv_b,
                 const float* __restrict__ proj_w, const float* __restrict__ proj_b,
                 float* __restrict__ out_vhw)
{
    int blk = blockIdx.x;             // 24 = 8 batches * 3 priors
    int b = blk / 3, p = blk % 3;
    int t = threadIdx.x;
    __shared__ float prr[96], vf[96];
    const float* src = (p == 0) ? uk : (p == 1) ? fg : bg;
    if (t < 96) prr[t] = src[b * 96 + t];
    __syncthreads();
    if (t < 96) {
        float acc = qkv_b[192 + t];
        for (int k = 0; k < 96; ++k)
            acc += prr[k] * qkv_w[(192 + t) * 96 + k];
        vf[t] = acc;
    }
    __syncthreads();
    if (t < 96) {
        float acc = proj_b[t];
        for (int c = 0; c < 96; ++c)
            acc += vf[c] * proj_w[t * 96 + c];
        out_vhw[(b * 3 + p) * 96 + t] = acc;
    }
}

extern "C" void kernel_launch(void* const* d_in, const int* in_sizes, int n_in,
                              void* d_out, int out_size, void* d_ws, size_t ws_size,
                              hipStream_t stream) {
    const float* x          = (const float*)d_in[0];
    const float* mask       = (const float*)d_in[1];
    const float* uk         = (const float*)d_in[2];
    const float* fg         = (const float*)d_in[3];
    const float* bg         = (const float*)d_in[4];
    const float* qkv_w      = (const float*)d_in[5];
    const float* qkv_b      = (const float*)d_in[6];
    const float* proj_w     = (const float*)d_in[7];
    const float* proj_b     = (const float*)d_in[8];
    const float* bias_table = (const float*)d_in[9];
    float* out = (float*)d_out;

    pawsa_prior<<<24, 128, 0, stream>>>(uk, fg, bg, qkv_w, qkv_b, proj_w, proj_b,
                                        out + (size_t)8192 * 49 * 96);
    pawsa_main<<<8192, 256, 0, stream>>>(x, mask, uk, fg, bg, qkv_w, qkv_b,
                                         proj_w, proj_b, bias_table, out);
}

// Round 11
// 377.394 us; speedup vs baseline: 2.2267x; 1.1604x over previous
//
#include <hip/hip_runtime.h>
#include <hip/hip_bf16.h>

// ---------------------------------------------------------------------------
// PAWSA fused windowed attention, MI355X / gfx950 — round 11: 4 blocks/CU.
// Inputs f32, output f32 (out0 [8192,49,96], out1 v_hw [8,3,96] at elem
// offset 38,535,168). One block per window (8192 x 256), bf16 MFMA 16x16x32.
// = R10 structure with LDS squeezed to 40,952 B (rounds to 40,960 = 160K/4):
//   XQ [49][100] (prior-q rows discarded per reference), K [52][100],
//   P [49][68], VT [96][68], BIAS [516]. Stride 100 = 50 words == 18 mod 32
//   (good bank spread); 8B row misalignment tolerated (proven by stride-68
//   reads passing since R5).
// Overread map (all finite or masked): XQ rows>48 -> K; K rows 52-63 -> P
// (masked -1e30 pre-exp, MFMA column isolation); P rows>48 -> VT; proj
// A rows>48 -> K.  Writes predicated: q/P/O rows<49, k rows<52.
// ---------------------------------------------------------------------------

typedef __bf16 bf16x8 __attribute__((ext_vector_type(8)));
typedef float  f32x4  __attribute__((ext_vector_type(4)));
using bf16 = __hip_bfloat16;

#define SCALE 0.17677669529663687f   // 32^-0.5

// LDS partition (units: 16-bit elements) — exact pack, 20,476 shorts = 40,952 B
#define LDS_XQ    0       // [49][100] x_ext rows<49 -> q -> O
#define LDS_K     4900    // [52][100] k
#define LDS_P     10100   // [49][68]  P (bf16 probs, per head)
#define LDS_VT    13432   // [96][68]  v transposed: vt[h*32+d][token]
#define LDS_BIAS  19960   // [516]     bias_table (bf16)
#define LDS_TOT   20476

static __device__ inline float s2f(short s) {
    unsigned int u = ((unsigned int)(unsigned short)s) << 16;
    float f;
    __builtin_memcpy(&f, &u, 4);
    return f;
}
static __device__ inline short f2s(float f) {
    bf16 h = __float2bfloat16(f);
    short s;
    __builtin_memcpy(&s, &h, 2);
    return s;
}
static __device__ inline bf16x8 ldw8(const float* p) {
    f32x4 a = *reinterpret_cast<const f32x4*>(p);
    f32x4 b = *reinterpret_cast<const f32x4*>(p + 4);
    bf16x8 r;
    #pragma unroll
    for (int i = 0; i < 4; ++i) {
        r[i]     = (__bf16)a[i];
        r[i + 4] = (__bf16)b[i];
    }
    return r;
}

__global__ __launch_bounds__(256, 4)
void pawsa_main(const float* __restrict__ x, const float* __restrict__ mask,
                const float* __restrict__ uk, const float* __restrict__ fg,
                const float* __restrict__ bg,
                const float* __restrict__ qkv_w, const float* __restrict__ qkv_b,
                const float* __restrict__ proj_w, const float* __restrict__ proj_b,
                const float* __restrict__ bias_table, float* __restrict__ out)
{
    __shared__ short smem[LDS_TOT];

    const int tid  = threadIdx.x;
    const int w    = blockIdx.x;       // window id
    const int b    = w >> 10;          // batch (nW = 1024)
    const int wi   = w & 1023;         // window-in-batch
    const int lane = tid & 63;
    const int wid  = tid >> 6;         // wave id 0..3
    const int lr   = lane & 15;        // row/col within 16-tile
    const int lg   = lane >> 4;        // k-group 0..3

    // ---- X tile -> registers directly (rows<49 x, 49-51 priors, >=52 zero) --
    bf16x8 af[3][4];
    #pragma unroll
    for (int mt = 0; mt < 4; ++mt) {
        int n = mt * 16 + lr;
        #pragma unroll
        for (int ks = 0; ks < 3; ++ks) {
            bf16x8 a = (bf16x8)0;
            if (n < 49) {
                a = ldw8(x + ((size_t)w * 49 + n) * 96 + ks * 32 + lg * 8);
            } else if (n < 52) {
                const float* pr = (n == 49) ? uk : (n == 50) ? fg : bg;
                a = ldw8(pr + b * 96 + ks * 32 + lg * 8);
            }
            af[ks][mt] = a;
        }
    }

    // ---- bias_table -> LDS (covered by the post-scatter barrier) ----
    for (int i = tid; i < 516; i += 256) smem[LDS_BIAS + i] = f2s(bias_table[i]);

    // ---- QKV GEMM: wave-split tiles (0-4,5-9,10-14,13-17; 13,14 dup benign),
    //      weights loaded per-tile (low register pressure), immediate scatter --
    const int nt0 = (wid < 3) ? wid * 5 : 13;
    #pragma unroll
    for (int i = 0; i < 5; ++i) {
        int o = (nt0 + i) * 16 + lr;          // output channel 0..287
        bf16x8 bw0 = ldw8(qkv_w + o * 96 + 0 * 32 + lg * 8);
        bf16x8 bw1 = ldw8(qkv_w + o * 96 + 1 * 32 + lg * 8);
        bf16x8 bw2 = ldw8(qkv_w + o * 96 + 2 * 32 + lg * 8);
        float  qb  = qkv_b[o];
        f32x4 acc[4] = {(f32x4)0.f, (f32x4)0.f, (f32x4)0.f, (f32x4)0.f};
        #pragma unroll
        for (int mt = 0; mt < 4; ++mt) {
            acc[mt] = __builtin_amdgcn_mfma_f32_16x16x32_bf16(af[0][mt], bw0, acc[mt], 0, 0, 0);
            acc[mt] = __builtin_amdgcn_mfma_f32_16x16x32_bf16(af[1][mt], bw1, acc[mt], 0, 0, 0);
            acc[mt] = __builtin_amdgcn_mfma_f32_16x16x32_bf16(af[2][mt], bw2, acc[mt], 0, 0, 0);
        }
        int s = o / 96;                       // 0=q 1=k 2=v
        int rem = o - s * 96;
        #pragma unroll
        for (int mt = 0; mt < 4; ++mt) {
            #pragma unroll
            for (int j = 0; j < 4; ++j) {
                int n = mt * 16 + lg * 4 + j;
                short hv = f2s(acc[mt][j] + qb);
                if (s == 0)      { if (n < 49) smem[LDS_XQ + n * 100 + rem] = hv; }
                else if (s == 1) { if (n < 52) smem[LDS_K  + n * 100 + rem] = hv; }
                else             smem[LDS_VT + rem * 68 + n] = hv;
            }
        }
    }

    // ---- mask loads (issued before barrier; consumed in heads) ----
    float mk[4][4];
    #pragma unroll
    for (int nt = 0; nt < 4; ++nt) {
        int c = nt * 16 + lr;
        #pragma unroll
        for (int j = 0; j < 4; ++j) {
            int n = wid * 16 + lg * 4 + j;
            float m = 0.f;
            if (c < 49 && n < 49)
                m = mask[(size_t)wi * 2401 + n * 49 + c];
            mk[nt][j] = m;
        }
    }

    __syncthreads();
    // From here: K, VT read-only; XQ/P rows wave-private.

    // REL_IDX packed (4 x u8 per int)
    int bidxp[4];
    #pragma unroll
    for (int nt = 0; nt < 4; ++nt) {
        int c = nt * 16 + lr;
        int p = 0;
        #pragma unroll
        for (int j = 0; j < 4; ++j) {
            int n = wid * 16 + lg * 4 + j;
            int idx = 171;
            if (c < 49) {
                idx = (n / 7 - c / 7 + 6) * 13 + ((n % 7) - (c % 7) + 6);
                if (idx > 171) idx = 171;     // garbage rows n>=49 (discarded)
            } else if (c < 52) {
                idx = 169 + (c - 49);
            }
            p |= idx << (8 * j);
        }
        bidxp[nt] = p;
    }

    // ---- per-head attention (wave-private rows; no barriers) ----
    #pragma unroll
    for (int h = 0; h < 3; ++h) {
        bf16x8 aq = *reinterpret_cast<const bf16x8*>(
            &smem[LDS_XQ + (wid * 16 + lr) * 100 + h * 32 + lg * 8]);
        f32x4 sacc[4];
        #pragma unroll
        for (int nt = 0; nt < 4; ++nt) {
            bf16x8 bk = *reinterpret_cast<const bf16x8*>(
                &smem[LDS_K + (nt * 16 + lr) * 100 + h * 32 + lg * 8]);
            sacc[nt] = __builtin_amdgcn_mfma_f32_16x16x32_bf16(aq, bk, (f32x4)0.f, 0, 0, 0);
        }
        float lgt[4][4];
        #pragma unroll
        for (int nt = 0; nt < 4; ++nt) {
            int c = nt * 16 + lr;
            #pragma unroll
            for (int j = 0; j < 4; ++j) {
                float v = -1e30f;
                if (c < 52) {
                    int idx = (bidxp[nt] >> (8 * j)) & 255;
                    v = sacc[nt][j] * SCALE
                        + s2f(smem[LDS_BIAS + idx * 3 + h]) + mk[nt][j];
                }
                lgt[nt][j] = v;
            }
        }
        float pr[4][4];
        #pragma unroll
        for (int j = 0; j < 4; ++j) {
            float m = fmaxf(fmaxf(lgt[0][j], lgt[1][j]), fmaxf(lgt[2][j], lgt[3][j]));
            m = fmaxf(m, __shfl_xor(m, 1));
            m = fmaxf(m, __shfl_xor(m, 2));
            m = fmaxf(m, __shfl_xor(m, 4));
            m = fmaxf(m, __shfl_xor(m, 8));
            float sum = 0.f;
            #pragma unroll
            for (int nt = 0; nt < 4; ++nt) {
                pr[nt][j] = __expf(lgt[nt][j] - m);
                sum += pr[nt][j];
            }
            sum += __shfl_xor(sum, 1);
            sum += __shfl_xor(sum, 2);
            sum += __shfl_xor(sum, 4);
            sum += __shfl_xor(sum, 8);
            float inv = 1.0f / sum;
            #pragma unroll
            for (int nt = 0; nt < 4; ++nt) pr[nt][j] *= inv;
        }
        #pragma unroll
        for (int nt = 0; nt < 4; ++nt)
            #pragma unroll
            for (int j = 0; j < 4; ++j) {
                int prow = wid * 16 + lg * 4 + j;
                if (prow < 49)
                    smem[LDS_P + prow * 68 + nt * 16 + lr] = f2s(pr[nt][j]);
            }

        // O_h = P @ V (K=52 padded to 64; P cols 52-63 exact zeros)
        f32x4 ov[2] = {(f32x4)0.f, (f32x4)0.f};
        #pragma unroll
        for (int ks = 0; ks < 2; ++ks) {
            bf16x8 ap = *reinterpret_cast<const bf16x8*>(
                &smem[LDS_P + (wid * 16 + lr) * 68 + ks * 32 + lg * 8]);
            #pragma unroll
            for (int nt2 = 0; nt2 < 2; ++nt2) {
                bf16x8 bv = *reinterpret_cast<const bf16x8*>(
                    &smem[LDS_VT + (h * 32 + nt2 * 16 + lr) * 68 + ks * 32 + lg * 8]);
                ov[nt2] = __builtin_amdgcn_mfma_f32_16x16x32_bf16(ap, bv, ov[nt2], 0, 0, 0);
            }
        }
        #pragma unroll
        for (int nt2 = 0; nt2 < 2; ++nt2)
            #pragma unroll
            for (int j = 0; j < 4; ++j) {
                int orow = wid * 16 + lg * 4 + j;
                if (orow < 49)
                    smem[LDS_XQ + orow * 100 + h * 32 + nt2 * 16 + lr]
                        = f2s(ov[nt2][j]);
            }
    }

    // ---- projection: [64x96] @ proj_w^T[96x96] (wave-private rows) ----
    f32x4 po[6];
    #pragma unroll
    for (int nt = 0; nt < 6; ++nt) po[nt] = (f32x4)0.f;
    #pragma unroll
    for (int ks = 0; ks < 3; ++ks) {
        bf16x8 a = *reinterpret_cast<const bf16x8*>(
            &smem[LDS_XQ + (wid * 16 + lr) * 100 + ks * 32 + lg * 8]);
        #pragma unroll
        for (int nt = 0; nt < 6; ++nt) {
            bf16x8 bp = ldw8(proj_w + (nt * 16 + lr) * 96 + ks * 32 + lg * 8);
            po[nt] = __builtin_amdgcn_mfma_f32_16x16x32_bf16(a, bp, po[nt], 0, 0, 0);
        }
    }
    #pragma unroll
    for (int nt = 0; nt < 6; ++nt) {
        float pb = proj_b[nt * 16 + lr];
        #pragma unroll
        for (int j = 0; j < 4; ++j) {
            int n = wid * 16 + lg * 4 + j;
            if (n < 49)
                out[((size_t)w * 49 + n) * 96 + nt * 16 + lr] = po[nt][j] + pb;
        }
    }
}

// ---------------- prior highway: v_hw = proj(v(qkv(prior))) ----------------
__global__ __launch_bounds__(128)
void pawsa_prior(const float* __restrict__ uk, const float* __restrict__ fg,
                 const float* __restrict__ bg,
                 const float* __restrict__ qkv_w, const float* __restrict__ qkv_b,
                 const float* __restrict__ proj_w, const float* __restrict__ proj_b,
                 float* __restrict__ out_vhw)
{
    int blk = blockIdx.x;             // 24 = 8 batches * 3 priors
    int b = blk / 3, p = blk % 3;
    int t = threadIdx.x;
    __shared__ float prr[96], vf[96];
    const float* src = (p == 0) ? uk : (p == 1) ? fg : bg;
    if (t < 96) prr[t] = src[b * 96 + t];
    __syncthreads();
    if (t < 96) {
        float acc = qkv_b[192 + t];
        for (int k = 0; k < 96; ++k)
            acc += prr[k] * qkv_w[(192 + t) * 96 + k];
        vf[t] = acc;
    }
    __syncthreads();
    if (t < 96) {
        float acc = proj_b[t];
        for (int c = 0; c < 96; ++c)
            acc += vf[c] * proj_w[t * 96 + c];
        out_vhw[(b * 3 + p) * 96 + t] = acc;
    }
}

extern "C" void kernel_launch(void* const* d_in, const int* in_sizes, int n_in,
                              void* d_out, int out_size, void* d_ws, size_t ws_size,
                              hipStream_t stream) {
    const float* x          = (const float*)d_in[0];
    const float* mask       = (const float*)d_in[1];
    const float* uk         = (const float*)d_in[2];
    const float* fg         = (const float*)d_in[3];
    const float* bg         = (const float*)d_in[4];
    const float* qkv_w      = (const float*)d_in[5];
    const float* qkv_b      = (const float*)d_in[6];
    const float* proj_w     = (const float*)d_in[7];
    const float* proj_b     = (const float*)d_in[8];
    const float* bias_table = (const float*)d_in[9];
    float* out = (float*)d_out;

    pawsa_prior<<<24, 128, 0, stream>>>(uk, fg, bg, qkv_w, qkv_b, proj_w, proj_b,
                                        out + (size_t)8192 * 49 * 96);
    pawsa_main<<<8192, 256, 0, stream>>>(x, mask, uk, fg, bg, qkv_w, qkv_b,
                                         proj_w, proj_b, bias_table, out);
}